// Round 1
// baseline (172.496 us; speedup 1.0000x reference)
//
#include <hip/hip_runtime.h>
#include <hip/hip_bf16.h>

// SelfAttentionBlock: B=4, C=256, RC=128, H=W=64 (N=4096)
// Pipeline: k_cvtw (weights->bf16) -> k_qkv (Q,K,V^T bf16) -> k_attn (flash) -> k_out (proj+residual)
// Workspace use: 4 weight arrays bf16 (256KB) + Q,K,Vt,O bf16 (4MB each) = ~16.3MB

#define B_   4
#define C_   256
#define RC_  128
#define N_   4096
#define SCALE 0.08838834764831845f  // 1/sqrt(128)

typedef __bf16 bf16x8 __attribute__((ext_vector_type(8)));
typedef unsigned short u16x8 __attribute__((ext_vector_type(8)));
typedef float f32x4 __attribute__((ext_vector_type(4)));

static __device__ __forceinline__ unsigned short f2bf(float f) {
    unsigned int u = __builtin_bit_cast(unsigned int, f);
    u += 0x7fffu + ((u >> 16) & 1u);   // round-to-nearest-even
    return (unsigned short)(u >> 16);
}

static __device__ __forceinline__ f32x4 mfma16(u16x8 a, u16x8 b, f32x4 c) {
    return __builtin_amdgcn_mfma_f32_16x16x32_bf16(
        __builtin_bit_cast(bf16x8, a), __builtin_bit_cast(bf16x8, b), c, 0, 0, 0);
}

// ---------------- kernel 0: convert weights to bf16 ----------------
__global__ __launch_bounds__(256) void k_cvtw(
    const float* __restrict__ wq, const float* __restrict__ wk,
    const float* __restrict__ wv, const float* __restrict__ wo,
    unsigned short* __restrict__ ws)
{
    int i = blockIdx.x * 256 + threadIdx.x;  // 0..131071
    const float* src; int off;
    if (i < 32768)       { src = wq; off = 0; }
    else if (i < 65536)  { src = wk; off = 32768; }
    else if (i < 98304)  { src = wv; off = 65536; }
    else                 { src = wo; off = 98304; }
    int j = i - off;
    ws[off + j] = f2bf(src[j]);
}

// ---------------- kernel 1: QKV projection ----------------
// Per block: 64 tokens x full RC=128 for Q,K,V.  x tile staged transposed ([n][c]) in LDS.
#define K1_LDA 264  // 256 + 8 pad (shorts); row stride 528B = 33*16B, bank-start 4n%32

__global__ __launch_bounds__(256) void k_qkv(
    const float* __restrict__ x, const unsigned short* __restrict__ wbf,
    const float* __restrict__ bq, const float* __restrict__ bk, const float* __restrict__ bv,
    unsigned short* __restrict__ Qb, unsigned short* __restrict__ Kb,
    unsigned short* __restrict__ Vt)
{
    __shared__ unsigned short lds[64 * K1_LDA];  // reused as Vt_tmp[128][72] in epilogue
    const int b  = blockIdx.y;
    const int n0 = blockIdx.x * 64;
    const int t  = threadIdx.x;
    const int lane = t & 63, wv_ = t >> 6;
    const int g = lane >> 4, q16 = lane & 15;

    // stage x[b][c][n0+lane] -> lds[n][c] (bf16), vectorized 8-c writes
    {
        const float* xb = x + ((size_t)b * C_ * N_) + n0 + lane;
        #pragma unroll
        for (int it = 0; it < 8; ++it) {
            int c0 = wv_ * 64 + it * 8;
            u16x8 v;
            #pragma unroll
            for (int e = 0; e < 8; ++e)
                v[e] = f2bf(xb[(size_t)(c0 + e) * N_]);
            *(u16x8*)&lds[lane * K1_LDA + c0] = v;
        }
    }
    __syncthreads();

    f32x4 acc[3][2][4];
    #pragma unroll
    for (int tq = 0; tq < 3; ++tq)
        #pragma unroll
        for (int r2 = 0; r2 < 2; ++r2)
            #pragma unroll
            for (int nf = 0; nf < 4; ++nf)
                acc[tq][r2][nf] = (f32x4){0.f, 0.f, 0.f, 0.f};

    const int rbase = wv_ * 32;
    #pragma unroll
    for (int ks = 0; ks < 8; ++ks) {
        u16x8 a[4];
        #pragma unroll
        for (int nf = 0; nf < 4; ++nf)
            a[nf] = *(const u16x8*)&lds[(nf * 16 + q16) * K1_LDA + ks * 32 + g * 8];
        #pragma unroll
        for (int tq = 0; tq < 3; ++tq) {
            const unsigned short* w = wbf + tq * 32768;
            #pragma unroll
            for (int r2 = 0; r2 < 2; ++r2) {
                u16x8 bf = *(const u16x8*)&w[(size_t)(rbase + r2 * 16 + q16) * 256 + ks * 32 + g * 8];
                #pragma unroll
                for (int nf = 0; nf < 4; ++nf)
                    acc[tq][r2][nf] = mfma16(a[nf], bf, acc[tq][r2][nf]);
            }
        }
    }

    // Q (pre-scaled) and K: direct bf16 stores  [B][N][RC]
    #pragma unroll
    for (int r2 = 0; r2 < 2; ++r2) {
        int r = rbase + r2 * 16 + q16;
        float biasq = bq[r], biask = bk[r];
        #pragma unroll
        for (int nf = 0; nf < 4; ++nf) {
            #pragma unroll
            for (int i = 0; i < 4; ++i) {
                int n = n0 + nf * 16 + g * 4 + i;
                size_t idx = ((size_t)b * N_ + n) * RC_ + r;
                Qb[idx] = f2bf((acc[0][r2][nf][i] + biasq) * SCALE);
                Kb[idx] = f2bf(acc[1][r2][nf][i] + biask);
            }
        }
    }

    // V: transpose through LDS, store Vt[B][RC][N]
    __syncthreads();
    #pragma unroll
    for (int r2 = 0; r2 < 2; ++r2) {
        int r = rbase + r2 * 16 + q16;
        float biasv = bv[r];
        #pragma unroll
        for (int nf = 0; nf < 4; ++nf)
            #pragma unroll
            for (int i = 0; i < 4; ++i)
                lds[r * 72 + nf * 16 + g * 4 + i] = f2bf(acc[2][r2][nf][i] + biasv);
    }
    __syncthreads();
    #pragma unroll
    for (int it = 0; it < 4; ++it) {
        int r = it * 32 + (t >> 3);
        int s = (t & 7) * 8;
        u16x8 v = *(const u16x8*)&lds[r * 72 + s];
        *(u16x8*)&Vt[((size_t)b * RC_ + r) * N_ + n0 + s] = v;
    }
}

// ---------------- kernel 2: flash attention ----------------
#define QS 136  // 128 + 8 pad (shorts), 272B stride
#define VS 72   // 64 + 8 pad (shorts), 144B stride

__global__ __launch_bounds__(256) void k_attn(
    const unsigned short* __restrict__ Qb, const unsigned short* __restrict__ Kb,
    const unsigned short* __restrict__ Vt, unsigned short* __restrict__ Ob)
{
    __shared__ unsigned short Ql[64 * QS];
    __shared__ unsigned short Kl[64 * QS];
    __shared__ unsigned short Vl[128 * VS];
    __shared__ unsigned short Pl[64 * VS];

    const int b  = blockIdx.y;
    const int n0 = blockIdx.x * 64;
    const int t  = threadIdx.x;
    const int lane = t & 63, wv_ = t >> 6;
    const int g = lane >> 4, q16 = lane & 15;

    // stage Q tile (consumed after first loop-top barrier)
    {
        const unsigned short* src = Qb + ((size_t)b * N_ + n0) * RC_;
        #pragma unroll
        for (int p = 0; p < 4; ++p) {
            int row = p * 16 + (t >> 4);
            int s = (t & 15) * 8;
            *(u16x8*)&Ql[row * QS + s] = *(const u16x8*)&src[row * RC_ + s];
        }
    }

    f32x4 acc_o[8];
    #pragma unroll
    for (int rf = 0; rf < 8; ++rf) acc_o[rf] = (f32x4){0.f, 0.f, 0.f, 0.f};
    float m_i[4], l_i[4];
    #pragma unroll
    for (int i = 0; i < 4; ++i) { m_i[i] = -1e30f; l_i[i] = 0.f; }

    for (int kt = 0; kt < 64; ++kt) {
        __syncthreads();  // previous iter's K/V reads done
        {
            const unsigned short* ksrc = Kb + ((size_t)b * N_ + kt * 64) * RC_;
            #pragma unroll
            for (int p = 0; p < 4; ++p) {
                int row = p * 16 + (t >> 4);
                int s = (t & 15) * 8;
                *(u16x8*)&Kl[row * QS + s] = *(const u16x8*)&ksrc[row * RC_ + s];
            }
            const unsigned short* vsrc = Vt + (size_t)b * RC_ * N_ + kt * 64;
            #pragma unroll
            for (int p = 0; p < 4; ++p) {
                int row = p * 32 + (t >> 3);
                int s = (t & 7) * 8;
                *(u16x8*)&Vl[row * VS + s] = *(const u16x8*)&vsrc[(size_t)row * N_ + s];
            }
        }
        __syncthreads();

        // S = Q K^T (scale folded into Q).  s_acc[jf][i] = S[g*4+i][jf*16+q16]
        f32x4 s_acc[4];
        #pragma unroll
        for (int jf = 0; jf < 4; ++jf) s_acc[jf] = (f32x4){0.f, 0.f, 0.f, 0.f};
        u16x8 a[4];
        #pragma unroll
        for (int ks = 0; ks < 4; ++ks)
            a[ks] = *(const u16x8*)&Ql[(wv_ * 16 + q16) * QS + ks * 32 + g * 8];
        #pragma unroll
        for (int jf = 0; jf < 4; ++jf) {
            #pragma unroll
            for (int ks = 0; ks < 4; ++ks) {
                u16x8 bf = *(const u16x8*)&Kl[(jf * 16 + q16) * QS + ks * 32 + g * 8];
                s_acc[jf] = mfma16(a[ks], bf, s_acc[jf]);
            }
        }

        // online softmax over the 16-lane row group
        float alpha[4];
        #pragma unroll
        for (int i = 0; i < 4; ++i) {
            float mx = fmaxf(fmaxf(s_acc[0][i], s_acc[1][i]),
                             fmaxf(s_acc[2][i], s_acc[3][i]));
            mx = fmaxf(mx, __shfl_xor(mx, 1));
            mx = fmaxf(mx, __shfl_xor(mx, 2));
            mx = fmaxf(mx, __shfl_xor(mx, 4));
            mx = fmaxf(mx, __shfl_xor(mx, 8));
            float m_new = fmaxf(m_i[i], mx);
            alpha[i] = __expf(m_i[i] - m_new);
            m_i[i] = m_new;
            float rs = 0.f;
            #pragma unroll
            for (int jf = 0; jf < 4; ++jf) {
                float p = __expf(s_acc[jf][i] - m_new);
                s_acc[jf][i] = p;
                rs += p;
            }
            rs += __shfl_xor(rs, 1);
            rs += __shfl_xor(rs, 2);
            rs += __shfl_xor(rs, 4);
            rs += __shfl_xor(rs, 8);
            l_i[i] = l_i[i] * alpha[i] + rs;
        }

        // stage P (bf16) into this wave's region; rescale O
        #pragma unroll
        for (int jf = 0; jf < 4; ++jf)
            #pragma unroll
            for (int i = 0; i < 4; ++i)
                Pl[(wv_ * 16 + g * 4 + i) * VS + jf * 16 + q16] = f2bf(s_acc[jf][i]);
        #pragma unroll
        for (int rf = 0; rf < 8; ++rf)
            #pragma unroll
            for (int i = 0; i < 4; ++i)
                acc_o[rf][i] *= alpha[i];
        __syncthreads();  // P visible (also keeps waves in lockstep)

        // O += P @ V
        u16x8 pa[2];
        #pragma unroll
        for (int ks = 0; ks < 2; ++ks)
            pa[ks] = *(const u16x8*)&Pl[(wv_ * 16 + q16) * VS + ks * 32 + g * 8];
        #pragma unroll
        for (int rf = 0; rf < 8; ++rf) {
            #pragma unroll
            for (int ks = 0; ks < 2; ++ks) {
                u16x8 vb = *(const u16x8*)&Vl[(rf * 16 + q16) * VS + ks * 32 + g * 8];
                acc_o[rf] = mfma16(pa[ks], vb, acc_o[rf]);
            }
        }
    }

    // final O = acc / l, store bf16 [B][N][RC]
    #pragma unroll
    for (int rf = 0; rf < 8; ++rf) {
        #pragma unroll
        for (int i = 0; i < 4; ++i) {
            int n = n0 + wv_ * 16 + g * 4 + i;
            Ob[((size_t)b * N_ + n) * RC_ + rf * 16 + q16] = f2bf(acc_o[rf][i] / l_i[i]);
        }
    }
}

// ---------------- kernel 3: output projection + residual ----------------
__global__ __launch_bounds__(256) void k_out(
    const unsigned short* __restrict__ Ob, const unsigned short* __restrict__ wobf,
    const float* __restrict__ bo, const float* __restrict__ x,
    const float* __restrict__ gamma, float* __restrict__ out)
{
    __shared__ unsigned short Ol[64 * QS];
    const int b  = blockIdx.z;
    const int c0 = blockIdx.y * 128;
    const int n0 = blockIdx.x * 64;
    const int t  = threadIdx.x;
    const int lane = t & 63, wv_ = t >> 6;
    const int g = lane >> 4, q16 = lane & 15;

    {
        const unsigned short* src = Ob + ((size_t)b * N_ + n0) * RC_;
        #pragma unroll
        for (int p = 0; p < 4; ++p) {
            int row = p * 16 + (t >> 4);
            int s = (t & 15) * 8;
            *(u16x8*)&Ol[row * QS + s] = *(const u16x8*)&src[row * RC_ + s];
        }
    }
    __syncthreads();

    f32x4 acc[2][4];
    #pragma unroll
    for (int cf = 0; cf < 2; ++cf)
        #pragma unroll
        for (int nf = 0; nf < 4; ++nf)
            acc[cf][nf] = (f32x4){0.f, 0.f, 0.f, 0.f};

    const int cw = c0 + wv_ * 32;
    #pragma unroll
    for (int ks = 0; ks < 4; ++ks) {
        u16x8 b8[4];
        #pragma unroll
        for (int nf = 0; nf < 4; ++nf)
            b8[nf] = *(const u16x8*)&Ol[(nf * 16 + q16) * QS + ks * 32 + g * 8];
        #pragma unroll
        for (int cf = 0; cf < 2; ++cf) {
            u16x8 a8 = *(const u16x8*)&wobf[(size_t)(cw + cf * 16 + q16) * 128 + ks * 32 + g * 8];
            #pragma unroll
            for (int nf = 0; nf < 4; ++nf)
                acc[cf][nf] = mfma16(a8, b8[nf], acc[cf][nf]);
        }
    }

    float gm = gamma[0];
    #pragma unroll
    for (int cf = 0; cf < 2; ++cf) {
        #pragma unroll
        for (int i = 0; i < 4; ++i) {
            int c = cw + cf * 16 + g * 4 + i;
            float bias = bo[c];
            #pragma unroll
            for (int nf = 0; nf < 4; ++nf) {
                int n = n0 + nf * 16 + q16;
                size_t idx = ((size_t)b * C_ + c) * N_ + n;
                out[idx] = gm * (acc[cf][nf][i] + bias) + x[idx];
            }
        }
    }
}

extern "C" void kernel_launch(void* const* d_in, const int* in_sizes, int n_in,
                              void* d_out, int out_size, void* d_ws, size_t ws_size,
                              hipStream_t stream) {
    const float* x     = (const float*)d_in[0];
    const float* wq    = (const float*)d_in[1];
    const float* bq    = (const float*)d_in[2];
    const float* wk    = (const float*)d_in[3];
    const float* bk    = (const float*)d_in[4];
    const float* wv    = (const float*)d_in[5];
    const float* bv    = (const float*)d_in[6];
    const float* wo    = (const float*)d_in[7];
    const float* bo    = (const float*)d_in[8];
    const float* gamma = (const float*)d_in[9];
    float* out = (float*)d_out;

    unsigned short* ws = (unsigned short*)d_ws;
    unsigned short* wbf  = ws;                 // wq,wk,wv (3*32768), wo at +98304
    unsigned short* wobf = ws + 98304;
    unsigned short* Qb   = ws + 131072;        // B*N*RC = 2097152 shorts each
    unsigned short* Kb   = Qb + 2097152;
    unsigned short* Vt   = Kb + 2097152;
    unsigned short* Ob   = Vt + 2097152;

    k_cvtw<<<512, 256, 0, stream>>>(wq, wk, wv, wo, ws);
    dim3 g1(64, 4);
    k_qkv<<<g1, 256, 0, stream>>>(x, wbf, bq, bk, bv, Qb, Kb, Vt);
    dim3 g2(64, 4);
    k_attn<<<g2, 256, 0, stream>>>(Qb, Kb, Vt, Ob);
    dim3 g3(64, 2, 4);
    k_out<<<g3, 256, 0, stream>>>(Ob, wobf, bo, x, gamma, out);
}